// Round 14
// baseline (190.861 us; speedup 1.0000x reference)
//
#include <hip/hip_runtime.h>
#include <hip/hip_bf16.h>
#include <hip/hip_fp16.h>
#include <cstdint>
#include <cstddef>

typedef _Float16 half8_t __attribute__((ext_vector_type(8)));
typedef float f32x4 __attribute__((ext_vector_type(4)));
typedef unsigned short ushort8_v __attribute__((ext_vector_type(8)));

// ---------------- prep: zero cnt + transpose-convert weights + zero dummy rows ----------------

__global__ __launch_bounds__(256) void prep_kernel(int* __restrict__ cnt, int N4,
                                                   const float* __restrict__ W1, _Float16* __restrict__ wt1,
                                                   const float* __restrict__ W2, _Float16* __restrict__ wt2,
                                                   const float* __restrict__ W3, _Float16* __restrict__ wt3,
                                                   _Float16* __restrict__ gA, _Float16* __restrict__ gB,
                                                   _Float16* __restrict__ gC, int N) {
  int i = blockIdx.x * 256 + threadIdx.x;
  if (i < N4) {
    *(int4*)&cnt[i * 4] = make_int4(0, 0, 0, 0);
    return;
  }
  int j = i - N4;
  if (j < 16384) {  // W1: 128x128
    int k = j >> 7, c = j & 127;
    wt1[c * 128 + k] = (_Float16)W1[j];
    return;
  }
  j -= 16384;
  if (j < 16384) {  // W2: 128x128
    int k = j >> 7, c = j & 127;
    wt2[c * 128 + k] = (_Float16)W2[j];
    return;
  }
  j -= 16384;
  if (j < 8192) {   // W3: 128x64
    int k = j >> 6, c = j & 63;
    wt3[c * 128 + k] = (_Float16)W3[j];
    return;
  }
  j -= 8192;
  if (j < 40) {     // zero dummy rows (row N of each message buffer)
    half8_t z = {};
    if (j < 16)       *(half8_t*)&gA[(size_t)N * 128 + j * 8] = z;
    else if (j < 32)  *(half8_t*)&gB[(size_t)N * 128 + (j - 16) * 8] = z;
    else              *(half8_t*)&gC[(size_t)N * 64 + (j - 32) * 8] = z;
  }
}

// ---------------- CSR construction (8-padded lists), 2 edges/thread ----------------

__global__ __launch_bounds__(256) void countpos_fill_kernel(const int* __restrict__ dst,
                                                            int* __restrict__ cnt,
                                                            ushort* __restrict__ pos, int E,
                                                            int* __restrict__ ssInt, int ssInts,
                                                            int countBlocks, int fillPat) {
  if (blockIdx.x >= countBlocks) {
    int f = ((blockIdx.x - countBlocks) * 256 + threadIdx.x) * 4;
    if (f + 4 <= ssInts) *(int4*)&ssInt[f] = make_int4(fillPat, fillPat, fillPat, fillPat);
    else for (; f < ssInts; ++f) ssInt[f] = fillPat;
    return;
  }
  int e = (blockIdx.x * blockDim.x + threadIdx.x) * 2;
  if (e + 2 <= E) {
    int2 d = *(const int2*)&dst[e];
    int p0 = atomicAdd(&cnt[d.x], 1);
    int p1 = atomicAdd(&cnt[d.y], 1);
    ushort2 pk;
    pk.x = (ushort)p0; pk.y = (ushort)p1;
    *(ushort2*)&pos[e] = pk;
  } else {
    for (; e < E; ++e) pos[e] = (ushort)atomicAdd(&cnt[dst[e]], 1);
  }
}

// ---------------- scans ----------------

__global__ __launch_bounds__(256) void block_sum_kernel(const int* __restrict__ cnt,
                                                        int* __restrict__ bsum, int N) {
  const int tid = threadIdx.x, lane = tid & 63, wid = tid >> 6;
  __shared__ int wt[4];
  int base = blockIdx.x * 2048 + tid * 8;
  int s = 0;
#pragma unroll
  for (int q = 0; q < 8; ++q) { int i = base + q; if (i < N) s += (cnt[i] + 7) & ~7; }
#pragma unroll
  for (int off = 32; off; off >>= 1) s += __shfl_down(s, off);
  if (lane == 0) wt[wid] = s;
  __syncthreads();
  if (tid == 0) bsum[blockIdx.x] = wt[0] + wt[1] + wt[2] + wt[3];
}

__global__ __launch_bounds__(256) void scan_bsum_kernel(const int* __restrict__ bsum,
                                                        int* __restrict__ boff,
                                                        int NB, int* __restrict__ rpN) {
  __shared__ int sh[256];
  const int tid = threadIdx.x;
  int v = (tid < NB) ? bsum[tid] : 0;
  sh[tid] = v;
  __syncthreads();
  for (int off = 1; off < 256; off <<= 1) {
    int t = (tid >= off) ? sh[tid - off] : 0;
    __syncthreads();
    sh[tid] += t;
    __syncthreads();
  }
  if (tid < NB) boff[tid] = sh[tid] - v;
  if (tid == 255) rpN[0] = sh[255];
}

__global__ __launch_bounds__(256) void scan_apply_kernel(const int* __restrict__ cnt,
                                                         const int* __restrict__ boff,
                                                         int* __restrict__ rp,
                                                         float* __restrict__ dis, int N) {
  const int tid = threadIdx.x, lane = tid & 63, wid = tid >> 6;
  __shared__ int wtot[4], wexc[4];
  int base = blockIdx.x * 2048 + tid * 8;
  int v[8]; int s = 0;
#pragma unroll
  for (int q = 0; q < 8; ++q) {
    int i = base + q; int x = (i < N) ? cnt[i] : 0;
    v[q] = x; s += (x + 7) & ~7;
  }
  int sc = s;
#pragma unroll
  for (int off = 1; off < 64; off <<= 1) { int t = __shfl_up(sc, off); if (lane >= off) sc += t; }
  if (lane == 63) wtot[wid] = sc;
  __syncthreads();
  if (tid == 0) { int r = 0; for (int wq = 0; wq < 4; ++wq) { wexc[wq] = r; r += wtot[wq]; } }
  __syncthreads();
  int thr = boff[blockIdx.x] + wexc[wid] + (sc - s);
#pragma unroll
  for (int q = 0; q < 8; ++q) {
    int i = base + q;
    if (i < N) { rp[i] = thr; dis[i] = rsqrtf((float)(v[q] + 1)); }
    thr += (v[q] + 7) & ~7;
  }
}

// ---------------- merged: place (scatter src into padded CSR) + GEMM-1 ----------------

__global__ __launch_bounds__(256) void place_gemm1_kernel(const int* __restrict__ src,
                                                          const int* __restrict__ dst,
                                                          const ushort* __restrict__ pos,
                                                          const int* __restrict__ rp,
                                                          ushort* __restrict__ ss, int E,
                                                          const float* __restrict__ X,
                                                          const half8_t* __restrict__ Wt,
                                                          const float* __restrict__ dis,
                                                          _Float16* __restrict__ G, int N,
                                                          int gemmBlocks) {
  if (blockIdx.x >= gemmBlocks) {
    int e = ((blockIdx.x - gemmBlocks) * blockDim.x + threadIdx.x) * 4;
    if (e + 4 <= E) {
      int4 d = *(const int4*)&dst[e];
      ushort4 p = *(const ushort4*)&pos[e];
      int4 s = *(const int4*)&src[e];
      int r0 = rp[d.x], r1 = rp[d.y], r2 = rp[d.z], r3 = rp[d.w];
      ss[r0 + p.x] = (ushort)s.x;
      ss[r1 + p.y] = (ushort)s.y;
      ss[r2 + p.z] = (ushort)s.z;
      ss[r3 + p.w] = (ushort)s.w;
    } else {
      for (; e < E; ++e) ss[rp[dst[e]] + pos[e]] = (ushort)src[e];
    }
    return;
  }
  const int wave = threadIdx.x >> 6;
  const int lane = threadIdx.x & 63;
  const int wm = wave >> 1, wn = wave & 1;
  const int row0 = blockIdx.x * 128 + wm * 64;
  const int col0 = wn * 64;
  const int lr = lane & 15;
  const int lk = lane >> 4;
  f32x4 acc[4][4];
#pragma unroll
  for (int r = 0; r < 4; ++r)
#pragma unroll
    for (int c = 0; c < 4; ++c) acc[r][c] = (f32x4){0.f, 0.f, 0.f, 0.f};

#pragma unroll
  for (int ks = 0; ks < 4; ++ks) {
    half8_t a[4], b[4];
#pragma unroll
    for (int r = 0; r < 4; ++r) {
      int row = row0 + r * 16 + lr;
      half8_t av = {};
      if (row < N) {
        const float* xp = &X[(size_t)row * 128 + ks * 32 + lk * 8];
        float4 xa = *(const float4*)xp;
        float4 xb = *(const float4*)(xp + 4);
        av[0] = (_Float16)xa.x; av[1] = (_Float16)xa.y; av[2] = (_Float16)xa.z; av[3] = (_Float16)xa.w;
        av[4] = (_Float16)xb.x; av[5] = (_Float16)xb.y; av[6] = (_Float16)xb.z; av[7] = (_Float16)xb.w;
      }
      a[r] = av;
    }
#pragma unroll
    for (int c = 0; c < 4; ++c) {
      int col = col0 + c * 16 + lr;
      b[c] = Wt[(size_t)col * 16 + ks * 4 + lk];
    }
#pragma unroll
    for (int r = 0; r < 4; ++r)
#pragma unroll
      for (int c = 0; c < 4; ++c)
        acc[r][c] = __builtin_amdgcn_mfma_f32_16x16x32_f16(a[r], b[c], acc[r][c], 0, 0, 0);
  }

#pragma unroll
  for (int r = 0; r < 4; ++r) {
#pragma unroll
    for (int q = 0; q < 4; ++q) {
      int row = row0 + r * 16 + lk * 4 + q;
      if (row < N) {
        float dv = dis[row];
#pragma unroll
        for (int c = 0; c < 4; ++c)
          G[(size_t)row * 128 + col0 + c * 16 + lr] = (_Float16)(acc[r][c][q] * dv);
      }
    }
  }
}

// ---------------- fused aggregate(layer i) + GEMM(layer i+1), 32 nodes/block ----------------
// 4-pass feature-sliced gather: pass p touches only bytes [p*64, p*64+64) of each G row
// (working set 3.2MB < 4MB per-XCD L2). Within a 16-lane group: ep=sub>>2 spreads lanes
// over 4 edges per instruction (16 cache lines/wave-instr, same density as before);
// fq=sub&3 picks the 16B sub-slice. shfl_xor(4,8) butterfly recombines edge partials.

template <int COUT>
__global__ __launch_bounds__(256) void fused_agg_gemm_kernel(const _Float16* __restrict__ G,
                                                             const int* __restrict__ rp,
                                                             const ushort* __restrict__ ss,
                                                             const float* __restrict__ dis,
                                                             const float* __restrict__ bias,
                                                             const half8_t* __restrict__ Wt,
                                                             _Float16* __restrict__ G2, int N) {
  __shared__ _Float16 sh[32][136];
  const int wave = threadIdx.x >> 6;
  const int lane = threadIdx.x & 63;
  const int grp = lane >> 4;
  const int sub = lane & 15;
  const int ep = sub >> 2;   // edge phase 0..3
  const int fq = sub & 3;    // feature-quarter sub-position 0..3
  const int nb0 = blockIdx.x * 32;

#pragma unroll
  for (int pass = 0; pass < 4; ++pass) {
#pragma unroll
    for (int it = 0; it < 2; ++it) {
      const int wl = it * 16 + wave * 4 + grp;
      const int w = nb0 + wl;
      if (w < N) {
        const int e0 = rp[w], e1 = rp[w + 1];
        float acc[8];
        if (ep == 0) {
          half8_t sv = *(const half8_t*)&G[(size_t)w * 128 + pass * 32 + fq * 8];
#pragma unroll
          for (int j = 0; j < 8; ++j) acc[j] = (float)sv[j];
        } else {
#pragma unroll
          for (int j = 0; j < 8; ++j) acc[j] = 0.f;
        }
        for (int e = e0; e < e1; e += 8) {
          ushort8_v iv = *(const ushort8_v*)&ss[e];
          int j0 = iv[ep], j1 = iv[4 + ep];
          half8_t v0 = *(const half8_t*)&G[(size_t)j0 * 128 + pass * 32 + fq * 8];
          half8_t v1 = *(const half8_t*)&G[(size_t)j1 * 128 + pass * 32 + fq * 8];
#pragma unroll
          for (int j = 0; j < 8; ++j) acc[j] += (float)v0[j] + (float)v1[j];
        }
#pragma unroll
        for (int j = 0; j < 8; ++j) acc[j] += __shfl_xor(acc[j], 4);
#pragma unroll
        for (int j = 0; j < 8; ++j) acc[j] += __shfl_xor(acc[j], 8);
        if (ep == 0) {
          float d = dis[w];
          float4 b0 = *(const float4*)&bias[pass * 32 + fq * 8];
          float4 b1 = *(const float4*)&bias[pass * 32 + fq * 8 + 4];
          float bb[8] = {b0.x, b0.y, b0.z, b0.w, b1.x, b1.y, b1.z, b1.w};
          half8_t o;
#pragma unroll
          for (int j = 0; j < 8; ++j) {
            float v = fmaxf(d * acc[j] + bb[j], 0.f);
            o[j] = (_Float16)v;
          }
          *(half8_t*)&sh[wl][pass * 32 + fq * 8] = o;
        }
      }
    }
  }
  __syncthreads();

  // ---- phase 2: 32 x COUT MFMA from LDS ----
  const int lr = lane & 15;
  const int lk = lane >> 4;
  constexpr int NC = COUT / 64;
  const int col0 = wave * (COUT / 4);
  f32x4 acc2[2][NC];
#pragma unroll
  for (int r = 0; r < 2; ++r)
#pragma unroll
    for (int c = 0; c < NC; ++c) acc2[r][c] = (f32x4){0.f, 0.f, 0.f, 0.f};

#pragma unroll
  for (int ks = 0; ks < 4; ++ks) {
    half8_t a[2], b[NC];
#pragma unroll
    for (int r = 0; r < 2; ++r)
      a[r] = *(const half8_t*)&sh[r * 16 + lr][ks * 32 + lk * 8];
#pragma unroll
    for (int c = 0; c < NC; ++c) {
      int col = col0 + c * 16 + lr;
      b[c] = Wt[(size_t)col * 16 + ks * 4 + lk];
    }
#pragma unroll
    for (int r = 0; r < 2; ++r)
#pragma unroll
      for (int c = 0; c < NC; ++c)
        acc2[r][c] = __builtin_amdgcn_mfma_f32_16x16x32_f16(a[r], b[c], acc2[r][c], 0, 0, 0);
  }

#pragma unroll
  for (int r = 0; r < 2; ++r) {
#pragma unroll
    for (int q = 0; q < 4; ++q) {
      int row = nb0 + r * 16 + lk * 4 + q;
      if (row < N) {
        float dv = dis[row];
#pragma unroll
        for (int c = 0; c < NC; ++c)
          G2[(size_t)row * COUT + col0 + c * 16 + lr] = (_Float16)(acc2[r][c][q] * dv);
      }
    }
  }
}

// ---------------- final aggregation (64-wide, fp32 out, no relu) ----------------
// 2-pass feature-sliced: pass p touches bytes [p*64, p*64+64) of each 128B gC row
// (working set 3.2MB). 8-lane groups: ep2=sub>>2 spreads over 2 edges/instr, fq=sub&3.

__global__ __launch_bounds__(256) void agg64_kernel(const _Float16* __restrict__ G,
                                                    const int* __restrict__ rp,
                                                    const ushort* __restrict__ ss,
                                                    const float* __restrict__ dis,
                                                    const float* __restrict__ bias,
                                                    float* __restrict__ OUT, int N) {
  const int wave = threadIdx.x >> 6;
  const int lane = threadIdx.x & 63;
  const int grp = lane >> 3;
  const int sub = lane & 7;
  const int ep2 = sub >> 2;  // 0..1
  const int fq = sub & 3;    // 0..3
  const int w = blockIdx.x * 32 + wave * 8 + grp;
  if (w >= N) return;
  const int e0 = rp[w], e1 = rp[w + 1];
  const float d = dis[w];

#pragma unroll
  for (int pass = 0; pass < 2; ++pass) {
    float acc[8];
    if (ep2 == 0) {
      half8_t sv = *(const half8_t*)&G[(size_t)w * 64 + pass * 32 + fq * 8];
#pragma unroll
      for (int j = 0; j < 8; ++j) acc[j] = (float)sv[j];
    } else {
#pragma unroll
      for (int j = 0; j < 8; ++j) acc[j] = 0.f;
    }
    for (int e = e0; e < e1; e += 8) {
      ushort8_v iv = *(const ushort8_v*)&ss[e];
#pragma unroll
      for (int q = 0; q < 4; ++q) {
        int jj = iv[q * 2 + ep2];
        half8_t v = *(const half8_t*)&G[(size_t)jj * 64 + pass * 32 + fq * 8];
#pragma unroll
        for (int j = 0; j < 8; ++j) acc[j] += (float)v[j];
      }
    }
#pragma unroll
    for (int j = 0; j < 8; ++j) acc[j] += __shfl_xor(acc[j], 4);
    if (ep2 == 0) {
      float4 b0 = *(const float4*)&bias[pass * 32 + fq * 8];
      float4 b1 = *(const float4*)&bias[pass * 32 + fq * 8 + 4];
      float4 o0, o1;
      o0.x = d * acc[0] + b0.x; o0.y = d * acc[1] + b0.y;
      o0.z = d * acc[2] + b0.z; o0.w = d * acc[3] + b0.w;
      o1.x = d * acc[4] + b1.x; o1.y = d * acc[5] + b1.y;
      o1.z = d * acc[6] + b1.z; o1.w = d * acc[7] + b1.w;
      *(float4*)&OUT[(size_t)w * 64 + pass * 32 + fq * 8] = o0;
      *(float4*)&OUT[(size_t)w * 64 + pass * 32 + fq * 8 + 4] = o1;
    }
  }
}

// ---------------- launch ----------------

extern "C" void kernel_launch(void* const* d_in, const int* in_sizes, int n_in,
                              void* d_out, int out_size, void* d_ws, size_t ws_size,
                              hipStream_t stream) {
  const float* x  = (const float*)d_in[0];
  const int*   ei = (const int*)d_in[1];
  const float* W1 = (const float*)d_in[2];
  const float* b1 = (const float*)d_in[3];
  const float* W2 = (const float*)d_in[4];
  const float* b2 = (const float*)d_in[5];
  const float* W3 = (const float*)d_in[6];
  const float* b3 = (const float*)d_in[7];

  const int inC = in_sizes[2] / in_sizes[3];  // 128
  const int N = in_sizes[0] / inC;            // 50000
  const int E = in_sizes[1] / 2;              // 800000

  const int SSPAD = ((E + 7 * N + 8) + 7) & ~7;

  auto align256 = [](size_t v) { return (v + 255) & ~(size_t)255; };
  char* p = (char*)d_ws;
  int* cnt = (int*)p;   p += align256((size_t)N * 4);
  int* rp  = (int*)p;   p += align256((size_t)(N + 1) * 4);
  ushort* ss = (ushort*)p;  p += align256((size_t)SSPAD * 2);
  ushort* pos = (ushort*)p; p += align256((size_t)E * 2);
  float* dis = (float*)p; p += align256((size_t)N * 4);
  _Float16* gA = (_Float16*)p; p += align256((size_t)(N + 1) * 128 * 2);
  _Float16* gB = (_Float16*)p; p += align256((size_t)(N + 1) * 128 * 2);
  _Float16* gC = (_Float16*)p; p += align256((size_t)(N + 1) * 64 * 2);
  _Float16* wt1 = (_Float16*)p; p += align256((size_t)128 * 128 * 2);
  _Float16* wt2 = (_Float16*)p; p += align256((size_t)128 * 128 * 2);
  _Float16* wt3 = (_Float16*)p; p += align256((size_t)64 * 128 * 2);
  int* bsum = (int*)p;  p += align256(1024 * 4);
  int* boff = (int*)p;  p += align256(1024 * 4);

  const int* srcv = ei;
  const int* dstv = ei + E;

  const int NB = (N + 2047) / 2048;
  const int eB2 = (E / 2 + 255) / 256;   // count blocks (2 edges/thread)
  const int eB4 = (E / 4 + 255) / 256;   // place blocks (4 edges/thread)
  const int N4 = (N + 3) / 4;
  const int prepTot = N4 + 16384 + 16384 + 8192 + 40;
  const int ssInts = SSPAD / 2;
  const int fillB = (ssInts / 4 + 255) / 256;
  const int fillPat = (int)(((unsigned)N) | (((unsigned)N) << 16));

  prep_kernel<<<(prepTot + 255) / 256, 256, 0, stream>>>(cnt, N4, W1, wt1, W2, wt2, W3, wt3,
                                                         gA, gB, gC, N);
  countpos_fill_kernel<<<eB2 + fillB, 256, 0, stream>>>(dstv, cnt, pos, E,
                                                        (int*)ss, ssInts, eB2, fillPat);
  block_sum_kernel<<<NB, 256, 0, stream>>>(cnt, bsum, N);
  scan_bsum_kernel<<<1, 256, 0, stream>>>(bsum, boff, NB, rp + N);
  scan_apply_kernel<<<NB, 256, 0, stream>>>(cnt, boff, rp, dis, N);

  const int g1B = (N + 127) / 128;
  const int fB  = (N + 31) / 32;
  const int a64B = (N + 31) / 32;

  place_gemm1_kernel<<<g1B + eB4, 256, 0, stream>>>(srcv, dstv, pos, rp, ss, E,
                                                    x, (const half8_t*)wt1, dis, gA, N, g1B);
  fused_agg_gemm_kernel<128><<<fB, 256, 0, stream>>>(gA, rp, ss, dis, b1, (const half8_t*)wt2, gB, N);
  fused_agg_gemm_kernel<64><<<fB, 256, 0, stream>>>(gB, rp, ss, dis, b2, (const half8_t*)wt3, gC, N);
  agg64_kernel<<<a64B, 256, 0, stream>>>(gC, rp, ss, dis, b3, (float*)d_out, N);
}

// Round 15
// 167.754 us; speedup vs baseline: 1.1377x; 1.1377x over previous
//
#include <hip/hip_runtime.h>
#include <hip/hip_bf16.h>
#include <hip/hip_fp16.h>
#include <cstdint>
#include <cstddef>

typedef _Float16 half8_t __attribute__((ext_vector_type(8)));
typedef float f32x4 __attribute__((ext_vector_type(4)));
typedef unsigned short ushort8_v __attribute__((ext_vector_type(8)));

// ---------------- prep: zero cnt + transpose-convert weights + zero dummy rows ----------------

__global__ __launch_bounds__(256) void prep_kernel(int* __restrict__ cnt, int N4,
                                                   const float* __restrict__ W1, _Float16* __restrict__ wt1,
                                                   const float* __restrict__ W2, _Float16* __restrict__ wt2,
                                                   const float* __restrict__ W3, _Float16* __restrict__ wt3,
                                                   _Float16* __restrict__ gA, _Float16* __restrict__ gB,
                                                   _Float16* __restrict__ gC, int N) {
  int i = blockIdx.x * 256 + threadIdx.x;
  if (i < N4) {
    *(int4*)&cnt[i * 4] = make_int4(0, 0, 0, 0);
    return;
  }
  int j = i - N4;
  if (j < 16384) {  // W1: 128x128
    int k = j >> 7, c = j & 127;
    wt1[c * 128 + k] = (_Float16)W1[j];
    return;
  }
  j -= 16384;
  if (j < 16384) {  // W2: 128x128
    int k = j >> 7, c = j & 127;
    wt2[c * 128 + k] = (_Float16)W2[j];
    return;
  }
  j -= 16384;
  if (j < 8192) {   // W3: 128x64
    int k = j >> 6, c = j & 63;
    wt3[c * 128 + k] = (_Float16)W3[j];
    return;
  }
  j -= 8192;
  if (j < 40) {     // zero dummy rows (row N of each message buffer)
    half8_t z = {};
    if (j < 16)       *(half8_t*)&gA[(size_t)N * 128 + j * 8] = z;
    else if (j < 32)  *(half8_t*)&gB[(size_t)N * 128 + (j - 16) * 8] = z;
    else              *(half8_t*)&gC[(size_t)N * 64 + (j - 32) * 8] = z;
  }
}

// ---------------- CSR construction (8-padded lists), 2 edges/thread ----------------

__global__ __launch_bounds__(256) void countpos_fill_kernel(const int* __restrict__ dst,
                                                            int* __restrict__ cnt,
                                                            ushort* __restrict__ pos, int E,
                                                            int* __restrict__ ssInt, int ssInts,
                                                            int countBlocks, int fillPat) {
  if (blockIdx.x >= countBlocks) {
    int f = ((blockIdx.x - countBlocks) * 256 + threadIdx.x) * 4;
    if (f + 4 <= ssInts) *(int4*)&ssInt[f] = make_int4(fillPat, fillPat, fillPat, fillPat);
    else for (; f < ssInts; ++f) ssInt[f] = fillPat;
    return;
  }
  int e = (blockIdx.x * blockDim.x + threadIdx.x) * 2;
  if (e + 2 <= E) {
    int2 d = *(const int2*)&dst[e];
    int p0 = atomicAdd(&cnt[d.x], 1);
    int p1 = atomicAdd(&cnt[d.y], 1);
    ushort2 pk;
    pk.x = (ushort)p0; pk.y = (ushort)p1;
    *(ushort2*)&pos[e] = pk;
  } else {
    for (; e < E; ++e) pos[e] = (ushort)atomicAdd(&cnt[dst[e]], 1);
  }
}

// ---------------- scans ----------------

__global__ __launch_bounds__(256) void block_sum_kernel(const int* __restrict__ cnt,
                                                        int* __restrict__ bsum, int N) {
  const int tid = threadIdx.x, lane = tid & 63, wid = tid >> 6;
  __shared__ int wt[4];
  int base = blockIdx.x * 2048 + tid * 8;
  int s = 0;
#pragma unroll
  for (int q = 0; q < 8; ++q) { int i = base + q; if (i < N) s += (cnt[i] + 7) & ~7; }
#pragma unroll
  for (int off = 32; off; off >>= 1) s += __shfl_down(s, off);
  if (lane == 0) wt[wid] = s;
  __syncthreads();
  if (tid == 0) bsum[blockIdx.x] = wt[0] + wt[1] + wt[2] + wt[3];
}

__global__ __launch_bounds__(256) void scan_bsum_kernel(const int* __restrict__ bsum,
                                                        int* __restrict__ boff,
                                                        int NB, int* __restrict__ rpN) {
  __shared__ int sh[256];
  const int tid = threadIdx.x;
  int v = (tid < NB) ? bsum[tid] : 0;
  sh[tid] = v;
  __syncthreads();
  for (int off = 1; off < 256; off <<= 1) {
    int t = (tid >= off) ? sh[tid - off] : 0;
    __syncthreads();
    sh[tid] += t;
    __syncthreads();
  }
  if (tid < NB) boff[tid] = sh[tid] - v;
  if (tid == 255) rpN[0] = sh[255];
}

__global__ __launch_bounds__(256) void scan_apply_kernel(const int* __restrict__ cnt,
                                                         const int* __restrict__ boff,
                                                         int* __restrict__ rp,
                                                         float* __restrict__ dis, int N) {
  const int tid = threadIdx.x, lane = tid & 63, wid = tid >> 6;
  __shared__ int wtot[4], wexc[4];
  int base = blockIdx.x * 2048 + tid * 8;
  int v[8]; int s = 0;
#pragma unroll
  for (int q = 0; q < 8; ++q) {
    int i = base + q; int x = (i < N) ? cnt[i] : 0;
    v[q] = x; s += (x + 7) & ~7;
  }
  int sc = s;
#pragma unroll
  for (int off = 1; off < 64; off <<= 1) { int t = __shfl_up(sc, off); if (lane >= off) sc += t; }
  if (lane == 63) wtot[wid] = sc;
  __syncthreads();
  if (tid == 0) { int r = 0; for (int wq = 0; wq < 4; ++wq) { wexc[wq] = r; r += wtot[wq]; } }
  __syncthreads();
  int thr = boff[blockIdx.x] + wexc[wid] + (sc - s);
#pragma unroll
  for (int q = 0; q < 8; ++q) {
    int i = base + q;
    if (i < N) { rp[i] = thr; dis[i] = rsqrtf((float)(v[q] + 1)); }
    thr += (v[q] + 7) & ~7;
  }
}

// ---------------- merged: place (scatter src into padded CSR) + GEMM-1 ----------------

__global__ __launch_bounds__(256) void place_gemm1_kernel(const int* __restrict__ src,
                                                          const int* __restrict__ dst,
                                                          const ushort* __restrict__ pos,
                                                          const int* __restrict__ rp,
                                                          ushort* __restrict__ ss, int E,
                                                          const float* __restrict__ X,
                                                          const half8_t* __restrict__ Wt,
                                                          const float* __restrict__ dis,
                                                          _Float16* __restrict__ G, int N,
                                                          int gemmBlocks) {
  if (blockIdx.x >= gemmBlocks) {
    int e = ((blockIdx.x - gemmBlocks) * blockDim.x + threadIdx.x) * 4;
    if (e + 4 <= E) {
      int4 d = *(const int4*)&dst[e];
      ushort4 p = *(const ushort4*)&pos[e];
      int4 s = *(const int4*)&src[e];
      int r0 = rp[d.x], r1 = rp[d.y], r2 = rp[d.z], r3 = rp[d.w];
      ss[r0 + p.x] = (ushort)s.x;
      ss[r1 + p.y] = (ushort)s.y;
      ss[r2 + p.z] = (ushort)s.z;
      ss[r3 + p.w] = (ushort)s.w;
    } else {
      for (; e < E; ++e) ss[rp[dst[e]] + pos[e]] = (ushort)src[e];
    }
    return;
  }
  const int wave = threadIdx.x >> 6;
  const int lane = threadIdx.x & 63;
  const int wm = wave >> 1, wn = wave & 1;
  const int row0 = blockIdx.x * 128 + wm * 64;
  const int col0 = wn * 64;
  const int lr = lane & 15;
  const int lk = lane >> 4;
  f32x4 acc[4][4];
#pragma unroll
  for (int r = 0; r < 4; ++r)
#pragma unroll
    for (int c = 0; c < 4; ++c) acc[r][c] = (f32x4){0.f, 0.f, 0.f, 0.f};

#pragma unroll
  for (int ks = 0; ks < 4; ++ks) {
    half8_t a[4], b[4];
#pragma unroll
    for (int r = 0; r < 4; ++r) {
      int row = row0 + r * 16 + lr;
      half8_t av = {};
      if (row < N) {
        const float* xp = &X[(size_t)row * 128 + ks * 32 + lk * 8];
        float4 xa = *(const float4*)xp;
        float4 xb = *(const float4*)(xp + 4);
        av[0] = (_Float16)xa.x; av[1] = (_Float16)xa.y; av[2] = (_Float16)xa.z; av[3] = (_Float16)xa.w;
        av[4] = (_Float16)xb.x; av[5] = (_Float16)xb.y; av[6] = (_Float16)xb.z; av[7] = (_Float16)xb.w;
      }
      a[r] = av;
    }
#pragma unroll
    for (int c = 0; c < 4; ++c) {
      int col = col0 + c * 16 + lr;
      b[c] = Wt[(size_t)col * 16 + ks * 4 + lk];
    }
#pragma unroll
    for (int r = 0; r < 4; ++r)
#pragma unroll
      for (int c = 0; c < 4; ++c)
        acc[r][c] = __builtin_amdgcn_mfma_f32_16x16x32_f16(a[r], b[c], acc[r][c], 0, 0, 0);
  }

#pragma unroll
  for (int r = 0; r < 4; ++r) {
#pragma unroll
    for (int q = 0; q < 4; ++q) {
      int row = row0 + r * 16 + lk * 4 + q;
      if (row < N) {
        float dv = dis[row];
#pragma unroll
        for (int c = 0; c < 4; ++c)
          G[(size_t)row * 128 + col0 + c * 16 + lr] = (_Float16)(acc[r][c][q] * dv);
      }
    }
  }
}

// ---------------- fused aggregate(layer i) + GEMM(layer i+1), 32 nodes/block ----------------

template <int COUT>
__global__ __launch_bounds__(256) void fused_agg_gemm_kernel(const _Float16* __restrict__ G,
                                                             const int* __restrict__ rp,
                                                             const ushort* __restrict__ ss,
                                                             const float* __restrict__ dis,
                                                             const float* __restrict__ bias,
                                                             const half8_t* __restrict__ Wt,
                                                             _Float16* __restrict__ G2, int N) {
  __shared__ _Float16 sh[32][136];
  const int wave = threadIdx.x >> 6;
  const int lane = threadIdx.x & 63;
  const int grp = lane >> 4;
  const int sub = lane & 15;
  const int nb0 = blockIdx.x * 32;

#pragma unroll
  for (int it = 0; it < 2; ++it) {
    const int wl = it * 16 + wave * 4 + grp;
    const int w = nb0 + wl;
    if (w < N) {
      const int e0 = rp[w], e1 = rp[w + 1];
      float acc[8];
      half8_t sv = *(const half8_t*)&G[(size_t)w * 128 + sub * 8];
#pragma unroll
      for (int j = 0; j < 8; ++j) acc[j] = (float)sv[j];
      for (int e = e0; e < e1; e += 8) {
        ushort8_v iv = *(const ushort8_v*)&ss[e];
        half8_t v[8];
#pragma unroll
        for (int q = 0; q < 8; ++q) v[q] = *(const half8_t*)&G[(size_t)iv[q] * 128 + sub * 8];
#pragma unroll
        for (int j = 0; j < 8; ++j)
          acc[j] += (((float)v[0][j] + (float)v[1][j]) + ((float)v[2][j] + (float)v[3][j])) +
                    (((float)v[4][j] + (float)v[5][j]) + ((float)v[6][j] + (float)v[7][j]));
      }
      float d = dis[w];
      float4 b0 = *(const float4*)&bias[sub * 8];
      float4 b1 = *(const float4*)&bias[sub * 8 + 4];
      float bb[8] = {b0.x, b0.y, b0.z, b0.w, b1.x, b1.y, b1.z, b1.w};
      half8_t o;
#pragma unroll
      for (int j = 0; j < 8; ++j) {
        float v = fmaxf(d * acc[j] + bb[j], 0.f);
        o[j] = (_Float16)v;
      }
      *(half8_t*)&sh[wl][sub * 8] = o;
    }
  }
  __syncthreads();

  const int lr = lane & 15;
  const int lk = lane >> 4;
  constexpr int NC = COUT / 64;
  const int col0 = wave * (COUT / 4);
  f32x4 acc2[2][NC];
#pragma unroll
  for (int r = 0; r < 2; ++r)
#pragma unroll
    for (int c = 0; c < NC; ++c) acc2[r][c] = (f32x4){0.f, 0.f, 0.f, 0.f};

#pragma unroll
  for (int ks = 0; ks < 4; ++ks) {
    half8_t a[2], b[NC];
#pragma unroll
    for (int r = 0; r < 2; ++r)
      a[r] = *(const half8_t*)&sh[r * 16 + lr][ks * 32 + lk * 8];
#pragma unroll
    for (int c = 0; c < NC; ++c) {
      int col = col0 + c * 16 + lr;
      b[c] = Wt[(size_t)col * 16 + ks * 4 + lk];
    }
#pragma unroll
    for (int r = 0; r < 2; ++r)
#pragma unroll
      for (int c = 0; c < NC; ++c)
        acc2[r][c] = __builtin_amdgcn_mfma_f32_16x16x32_f16(a[r], b[c], acc2[r][c], 0, 0, 0);
  }

#pragma unroll
  for (int r = 0; r < 2; ++r) {
#pragma unroll
    for (int q = 0; q < 4; ++q) {
      int row = nb0 + r * 16 + lk * 4 + q;
      if (row < N) {
        float dv = dis[row];
#pragma unroll
        for (int c = 0; c < NC; ++c)
          G2[(size_t)row * COUT + col0 + c * 16 + lr] = (_Float16)(acc2[r][c][q] * dv);
      }
    }
  }
}

// ---------------- final aggregation (64-wide, fp32 out, no relu) ----------------

__global__ __launch_bounds__(256) void agg64_kernel(const _Float16* __restrict__ G,
                                                    const int* __restrict__ rp,
                                                    const ushort* __restrict__ ss,
                                                    const float* __restrict__ dis,
                                                    const float* __restrict__ bias,
                                                    float* __restrict__ OUT, int N) {
  const int wave = threadIdx.x >> 6;
  const int lane = threadIdx.x & 63;
  const int grp = lane >> 3;
  const int sub = lane & 7;
  const int w = blockIdx.x * 32 + wave * 8 + grp;
  if (w >= N) return;
  const int e0 = rp[w], e1 = rp[w + 1];
  float acc[8];
  half8_t sv = *(const half8_t*)&G[(size_t)w * 64 + sub * 8];
#pragma unroll
  for (int j = 0; j < 8; ++j) acc[j] = (float)sv[j];
  for (int e = e0; e < e1; e += 8) {
    ushort8_v iv = *(const ushort8_v*)&ss[e];
    half8_t v[8];
#pragma unroll
    for (int q = 0; q < 8; ++q) v[q] = *(const half8_t*)&G[(size_t)iv[q] * 64 + sub * 8];
#pragma unroll
    for (int j = 0; j < 8; ++j)
      acc[j] += (((float)v[0][j] + (float)v[1][j]) + ((float)v[2][j] + (float)v[3][j])) +
                (((float)v[4][j] + (float)v[5][j]) + ((float)v[6][j] + (float)v[7][j]));
  }
  float d = dis[w];
  float4 b0 = *(const float4*)&bias[sub * 8];
  float4 b1 = *(const float4*)&bias[sub * 8 + 4];
  float4 o0, o1;
  o0.x = d * acc[0] + b0.x; o0.y = d * acc[1] + b0.y;
  o0.z = d * acc[2] + b0.z; o0.w = d * acc[3] + b0.w;
  o1.x = d * acc[4] + b1.x; o1.y = d * acc[5] + b1.y;
  o1.z = d * acc[6] + b1.z; o1.w = d * acc[7] + b1.w;
  *(float4*)&OUT[(size_t)w * 64 + sub * 8] = o0;
  *(float4*)&OUT[(size_t)w * 64 + sub * 8 + 4] = o1;
}

// ---------------- launch ----------------

extern "C" void kernel_launch(void* const* d_in, const int* in_sizes, int n_in,
                              void* d_out, int out_size, void* d_ws, size_t ws_size,
                              hipStream_t stream) {
  const float* x  = (const float*)d_in[0];
  const int*   ei = (const int*)d_in[1];
  const float* W1 = (const float*)d_in[2];
  const float* b1 = (const float*)d_in[3];
  const float* W2 = (const float*)d_in[4];
  const float* b2 = (const float*)d_in[5];
  const float* W3 = (const float*)d_in[6];
  const float* b3 = (const float*)d_in[7];

  const int inC = in_sizes[2] / in_sizes[3];  // 128
  const int N = in_sizes[0] / inC;            // 50000
  const int E = in_sizes[1] / 2;              // 800000

  const int SSPAD = ((E + 7 * N + 8) + 7) & ~7;

  auto align256 = [](size_t v) { return (v + 255) & ~(size_t)255; };
  char* p = (char*)d_ws;
  int* cnt = (int*)p;   p += align256((size_t)N * 4);
  int* rp  = (int*)p;   p += align256((size_t)(N + 1) * 4);
  ushort* ss = (ushort*)p;  p += align256((size_t)SSPAD * 2);
  ushort* pos = (ushort*)p; p += align256((size_t)E * 2);
  float* dis = (float*)p; p += align256((size_t)N * 4);
  _Float16* gA = (_Float16*)p; p += align256((size_t)(N + 1) * 128 * 2);
  _Float16* gB = (_Float16*)p; p += align256((size_t)(N + 1) * 128 * 2);
  _Float16* gC = (_Float16*)p; p += align256((size_t)(N + 1) * 64 * 2);
  _Float16* wt1 = (_Float16*)p; p += align256((size_t)128 * 128 * 2);
  _Float16* wt2 = (_Float16*)p; p += align256((size_t)128 * 128 * 2);
  _Float16* wt3 = (_Float16*)p; p += align256((size_t)64 * 128 * 2);
  int* bsum = (int*)p;  p += align256(1024 * 4);
  int* boff = (int*)p;  p += align256(1024 * 4);

  const int* srcv = ei;
  const int* dstv = ei + E;

  const int NB = (N + 2047) / 2048;
  const int eB2 = (E / 2 + 255) / 256;   // count blocks (2 edges/thread)
  const int eB4 = (E / 4 + 255) / 256;   // place blocks (4 edges/thread)
  const int N4 = (N + 3) / 4;
  const int prepTot = N4 + 16384 + 16384 + 8192 + 40;
  const int ssInts = SSPAD / 2;
  const int fillB = (ssInts / 4 + 255) / 256;
  const int fillPat = (int)(((unsigned)N) | (((unsigned)N) << 16));

  prep_kernel<<<(prepTot + 255) / 256, 256, 0, stream>>>(cnt, N4, W1, wt1, W2, wt2, W3, wt3,
                                                         gA, gB, gC, N);
  countpos_fill_kernel<<<eB2 + fillB, 256, 0, stream>>>(dstv, cnt, pos, E,
                                                        (int*)ss, ssInts, eB2, fillPat);
  block_sum_kernel<<<NB, 256, 0, stream>>>(cnt, bsum, N);
  scan_bsum_kernel<<<1, 256, 0, stream>>>(bsum, boff, NB, rp + N);
  scan_apply_kernel<<<NB, 256, 0, stream>>>(cnt, boff, rp, dis, N);

  const int g1B = (N + 127) / 128;
  const int fB  = (N + 31) / 32;
  const int a64B = (N + 31) / 32;

  place_gemm1_kernel<<<g1B + eB4, 256, 0, stream>>>(srcv, dstv, pos, rp, ss, E,
                                                    x, (const half8_t*)wt1, dis, gA, N, g1B);
  fused_agg_gemm_kernel<128><<<fB, 256, 0, stream>>>(gA, rp, ss, dis, b1, (const half8_t*)wt2, gB, N);
  fused_agg_gemm_kernel<64><<<fB, 256, 0, stream>>>(gB, rp, ss, dis, b2, (const half8_t*)wt3, gC, N);
  agg64_kernel<<<a64B, 256, 0, stream>>>(gC, rp, ss, dis, b3, (float*)d_out, N);
}